// Round 11
// baseline (466.892 us; speedup 1.0000x reference)
//
#include <hip/hip_runtime.h>
#include <hip/hip_bf16.h>

typedef unsigned short u16;
typedef __attribute__((ext_vector_type(8))) short frag8;   // 8 bf16
typedef __attribute__((ext_vector_type(4))) float facc4;   // 4 f32

#define L_SEQ 2048
#define D_MODEL 2048
#define N_HEADS 16
#define HEAD_D 128
#define N_QKV 6144
#define D_INNER 8192

__device__ __forceinline__ u16 f2b(float f) {
    __hip_bfloat16 h = __float2bfloat16(f);
    return *reinterpret_cast<u16*>(&h);
}

__device__ __forceinline__ float b2f(u16 u) {
    __hip_bfloat16 h = *reinterpret_cast<__hip_bfloat16*>(&u);
    return __bfloat162float(h);
}

__device__ __forceinline__ void gload_lds16(const void* g, void* l) {
    __builtin_amdgcn_global_load_lds(
        (const __attribute__((address_space(1))) unsigned int*)g,
        (__attribute__((address_space(3))) unsigned int*)l, 16, 0, 0);
}

__device__ __forceinline__ float gelu_exact(float x) {
    return 0.5f * x * (1.0f + erff(x * 0.7071067811865475f));
}

// ---------------- elementwise f32 -> bf16 (vectorized) ----------------
__global__ __launch_bounds__(256) void cvt_bf16_kernel(const float* __restrict__ in, u16* __restrict__ out, int n) {
    const int i = (blockIdx.x * 256 + threadIdx.x) * 8;
    if (i >= n) return;
    float4 a = *(const float4*)(in + i);
    float4 b = *(const float4*)(in + i + 4);
    u16 tmp[8];
    tmp[0] = f2b(a.x); tmp[1] = f2b(a.y); tmp[2] = f2b(a.z); tmp[3] = f2b(a.w);
    tmp[4] = f2b(b.x); tmp[5] = f2b(b.y); tmp[6] = f2b(b.z); tmp[7] = f2b(b.w);
    *(uint4*)(out + i) = *(uint4*)tmp;
}

// ---------------- transpose + convert: f32 [R][C] -> bf16 [C][R], 64x64 tiles ----------------
__global__ __launch_bounds__(256) void tr_cvt64(const float* __restrict__ in, u16* __restrict__ out, int R, int C) {
    __shared__ float t[64][68];
    const int bx = blockIdx.x * 64;  // C dim
    const int by = blockIdx.y * 64;  // R dim
    const int tid = threadIdx.x;
    {
        const int r = tid >> 2;
        const int c4 = (tid & 3) * 16;
        const float* src = in + (size_t)(by + r) * C + bx + c4;
#pragma unroll
        for (int j = 0; j < 4; ++j)
            *(float4*)&t[r][c4 + 4 * j] = *(const float4*)(src + 4 * j);
    }
    __syncthreads();
    {
        const int cc = tid >> 2;
        const int rr0 = (tid & 3) * 16;
        u16 tmp[16];
#pragma unroll
        for (int j = 0; j < 16; ++j) tmp[j] = f2b(t[rr0 + j][cc]);
        u16* dst = out + (size_t)(bx + cc) * R + by + rr0;
        *(uint4*)(dst) = *(uint4*)&tmp[0];
        *(uint4*)(dst + 8) = *(uint4*)&tmp[8];
    }
}

// ---------------- legacy 128x128 GEMM (proj) ----------------
__global__ __launch_bounds__(256) void gemm_bt(const u16* __restrict__ A, const u16* __restrict__ Bt,
                                               const float* __restrict__ bias, float* __restrict__ Cout,
                                               int M, int N, int K) {
    __shared__ u16 lA[128 * 64];
    __shared__ u16 lB[128 * 64];
    const int tid = threadIdx.x;
    const int lane = tid & 63, wid = tid >> 6;
    const int wr = wid >> 1, wc = wid & 1;
    const int l15 = lane & 15, g4 = lane >> 4;
    const int bm = blockIdx.y, bn = blockIdx.x;

    const int arow = tid >> 3;
    const int acol = (tid & 7) * 8;
    const size_t abase = (size_t)(bm * 128) * K + acol;
    const size_t bbase = (size_t)(bn * 128) * K + acol;

    facc4 acc[4][4] = {};

    for (int k0 = 0; k0 < K; k0 += 64) {
        if (k0) __syncthreads();
#pragma unroll
        for (int i = 0; i < 4; i++) {
            gload_lds16(A + abase + (size_t)(i * 32 + arow) * K + k0, &lA[i * 2048 + tid * 8]);
            gload_lds16(Bt + bbase + (size_t)(i * 32 + arow) * K + k0, &lB[i * 2048 + tid * 8]);
        }
        __syncthreads();
#pragma unroll
        for (int kk = 0; kk < 64; kk += 32) {
            frag8 af[4], bf[4];
#pragma unroll
            for (int m = 0; m < 4; m++)
                af[m] = *(const frag8*)&lA[(wr * 64 + m * 16 + l15) * 64 + kk + g4 * 8];
#pragma unroll
            for (int n = 0; n < 4; n++)
                bf[n] = *(const frag8*)&lB[(wc * 64 + n * 16 + l15) * 64 + kk + g4 * 8];
#pragma unroll
            for (int m = 0; m < 4; m++)
#pragma unroll
                for (int n = 0; n < 4; n++)
                    acc[m][n] = __builtin_amdgcn_mfma_f32_16x16x32_bf16(af[m], bf[n], acc[m][n], 0, 0, 0);
        }
    }

    const int row0 = bm * 128 + wr * 64 + g4 * 4;
    const int col0 = bn * 128 + wc * 64 + l15;
#pragma unroll
    for (int n = 0; n < 4; n++) {
        const int col = col0 + n * 16;
        const float bv = bias[col];
#pragma unroll
        for (int m = 0; m < 4; m++)
#pragma unroll
            for (int r = 0; r < 4; r++)
                Cout[(size_t)(row0 + m * 16 + r) * N + col] = acc[m][n][r] + bv;
    }
}

// ---------------- gemm256 v10 (kept): 256x256, BK=64, 2 dbuf, 4-phase counted-vmcnt ----------------
// EPI: 0 f32+bias, 1 bf16+bias, 2 gelu+bf16+bias, 3 bf16 partial (plane by blockIdx.z, no bias)
template <int EPI>
__global__ __launch_bounds__(512, 2) void gemm256(const u16* __restrict__ A, const u16* __restrict__ Bt,
                                                  const float* __restrict__ bias, void* __restrict__ Cout,
                                                  u16* __restrict__ q0, u16* __restrict__ q1,
                                                  u16* __restrict__ q2, u16* __restrict__ q3,
                                                  int M, int N, int K, int kseg, int nbm) {
    __shared__ u16 lds[2 * 32768];  // buf d: A-h0 @ d*32768, A-h1 @ +8192, B-h0 @ +16384, B-h1 @ +24576
    const int tid = threadIdx.x;
    const int lane = tid & 63, wid = tid >> 6;
    const int wm = wid >> 2, wn = wid & 3;
    const int l15 = lane & 15, g4 = lane >> 4;

    const int nwg = gridDim.x;
    const int q8 = nwg >> 3;
    const int wg = (blockIdx.x & 7) * q8 + (blockIdx.x >> 3);
    const int bm = wg % nbm, bn = wg / nbm;
    const int kb = blockIdx.z * kseg;
    const int ksz = (blockIdx.z == (int)gridDim.z - 1) ? (K - kb) : kseg;
    const int nt = ksz >> 6;  // BK=64 tiles

    const int rr = tid >> 3;
    const int kk8 = tid & 7;
    const int srcE = (kk8 ^ (rr & 7)) << 3;
    const u16* aS = A + (size_t)(bm * 256 + rr) * K + kb + srcE;
    const u16* bS = Bt + (size_t)(bn * 256 + ((rr >> 5) << 6) + (rr & 31)) * K + kb + srcE;
    const size_t r128 = (size_t)128 * K;
    const size_t r64 = (size_t)64 * K;
    const size_t c32 = (size_t)32 * K;

    auto stA = [&](int tt, int h) {
        u16* d = &lds[((tt & 1) << 15) + (h << 13)];
        const u16* g = aS + (size_t)tt * 64 + (h ? r64 : 0);
        gload_lds16(g, d + tid * 8);
        gload_lds16(g + r128, d + 4096 + tid * 8);
    };
    auto stB = [&](int tt, int h) {
        u16* d = &lds[((tt & 1) << 15) + 16384 + (h << 13)];
        const u16* g = bS + (size_t)tt * 64 + (h ? c32 : 0);
        gload_lds16(g, d + tid * 8);
        gload_lds16(g + r128, d + 4096 + tid * 8);
    };

    const int ch0 = (g4 ^ (l15 & 7)) << 3;
    const int ch1 = ch0 ^ 32;
    const int aRdBase = (wm * 64 + l15) * 64;
    const int bRdBase = (wn * 32 + l15) * 64;

    frag8 a[4][2], b0[2][2], b1[2][2];
    facc4 acc[8][4] = {};

    auto rdA = [&](int bufo, int mh) {
#pragma unroll
        for (int mi = 0; mi < 4; ++mi) {
            const int base = bufo + mh * 8192 + aRdBase + mi * 1024;
            a[mi][0] = *(const frag8*)&lds[base + ch0];
            a[mi][1] = *(const frag8*)&lds[base + ch1];
        }
    };
    auto rdB = [&](int bufo, int nh, frag8(&bb)[2][2]) {
#pragma unroll
        for (int ni = 0; ni < 2; ++ni) {
            const int base = bufo + 16384 + nh * 8192 + bRdBase + ni * 1024;
            bb[ni][0] = *(const frag8*)&lds[base + ch0];
            bb[ni][1] = *(const frag8*)&lds[base + ch1];
        }
    };
    auto quad = [&](int mh, int nh, frag8(&bb)[2][2]) {
        __builtin_amdgcn_s_setprio(1);
#pragma unroll
        for (int kh = 0; kh < 2; ++kh)
#pragma unroll
            for (int mi = 0; mi < 4; ++mi)
#pragma unroll
                for (int ni = 0; ni < 2; ++ni)
                    acc[mh * 4 + mi][nh * 2 + ni] =
                        __builtin_amdgcn_mfma_f32_16x16x32_bf16(a[mi][kh], bb[ni][kh],
                                                                acc[mh * 4 + mi][nh * 2 + ni], 0, 0, 0);
        __builtin_amdgcn_s_setprio(0);
    };

#define SB __builtin_amdgcn_sched_barrier(0)
#define BAR __builtin_amdgcn_s_barrier()

    stA(0, 0); stB(0, 0); stB(0, 1); stA(0, 1);
    asm volatile("s_waitcnt vmcnt(4)" ::: "memory");
    BAR; SB;

    for (int t = 0; t < nt; ++t) {
        const int bufo = (t & 1) << 15;
        const bool so = (t + 1 < nt);
        // phase 0
        rdA(bufo, 0);
        rdB(bufo, 0, b0);
        if (so) stA(t + 1, 0);
        SB; BAR; SB;
        quad(0, 0, b0);
        if (so) asm volatile("s_waitcnt vmcnt(4)" ::: "memory");
        else    asm volatile("s_waitcnt vmcnt(2)" ::: "memory");
        BAR; SB;
        // phase 1
        rdB(bufo, 1, b1);
        if (so) stB(t + 1, 0);
        SB; BAR; SB;
        quad(0, 1, b1);
        if (so) asm volatile("s_waitcnt vmcnt(4)" ::: "memory");
        else    asm volatile("s_waitcnt vmcnt(0)" ::: "memory");
        BAR; SB;
        // phase 2
        rdA(bufo, 1);
        if (so) stB(t + 1, 1);
        SB; BAR; SB;
        quad(1, 0, b0);
        BAR; SB;
        // phase 3
        if (so) stA(t + 1, 1);
        SB; BAR; SB;
        quad(1, 1, b1);
        if (so) asm volatile("s_waitcnt vmcnt(4)" ::: "memory");
        BAR; SB;
    }
#undef SB
#undef BAR

    // epilogue
    const int row0 = bm * 256 + wm * 128 + g4 * 4;
    const int col0 = bn * 256 + wn * 64 + l15;
    u16* pout = nullptr;
    if (EPI == 3) {
        const int z = blockIdx.z;
        pout = (z == 0) ? q0 : (z == 1) ? q1 : (z == 2) ? q2 : q3;
    }
#pragma unroll
    for (int nf = 0; nf < 4; nf++) {
        const int col = col0 + nf * 16;
        const float bv = (EPI == 3) ? 0.0f : bias[col];
#pragma unroll
        for (int mf = 0; mf < 8; mf++) {
#pragma unroll
            for (int r = 0; r < 4; r++) {
                const int row = row0 + mf * 16 + r;
                float v = acc[mf][nf][r] + bv;
                if (EPI == 2) v = gelu_exact(v);
                if (EPI == 0)
                    ((float*)Cout)[(size_t)row * N + col] = v;
                else if (EPI == 3)
                    pout[(size_t)row * N + col] = f2b(v);
                else
                    ((u16*)Cout)[(size_t)row * N + col] = f2b(v);
            }
        }
    }
}

// ---------------- flash attention v8: K/V double-buffered, T14 async-stage split ----------------
// 4 waves/block, 64 q-rows/block, KVBLK=64. Per tile t: issue K-DMA + V-reg loads for t+1,
// compute tile t from buf, write V regs -> LDS(buf^1), one __syncthreads (drains K DMA).
__global__ __launch_bounds__(256) void attn_kernel(const u16* __restrict__ qkv, u16* __restrict__ out) {
    __shared__ u16 kT[2][64 * 128];
    __shared__ u16 vT[2][128 * 64];
    const int h = blockIdx.y;
    const int qb = (blockIdx.y < 8) ? ((int)gridDim.x - 1 - (int)blockIdx.x) : (int)blockIdx.x;
    const int tid = threadIdx.x;
    const int lane = tid & 63, w = tid >> 6;
    const int l15 = lane & 15, g4 = lane >> 4;
    const int q0 = qb * 64 + w * 16;
    const float scale = 0.022097086912079608f;  // 1/sqrt(2048)

    // staging index precompute (K)
    const int sk_row = tid >> 2;                       // rows 0..63 over p-loop (c>>4)
    // Q fragments
    frag8 qf[4];
    {
        const u16* qrow = qkv + (size_t)(q0 + l15) * N_QKV + h * HEAD_D + g4 * 8;
#pragma unroll
        for (int c = 0; c < 4; c++) qf[c] = *(const frag8*)(qrow + c * 32);
    }

    float m_run = -1e30f, l_run = 0.0f;
    facc4 o[8] = {};

    const int src0 = ((g4 & 1) << 5) + l15;
    const int src1 = src0 + 16;
    const bool hi = (g4 & 2) != 0;

    const int nt = qb + 1;

    auto stageK = [&](int kbase, int buf) {
        const u16* kg_ptr = qkv + (size_t)kbase * N_QKV + D_MODEL + h * HEAD_D;
#pragma unroll
        for (int p = 0; p < 4; ++p) {
            const int c = p * 256 + tid;
            const int row = c >> 4;
            const int colb = (c & 15) << 4;
            const int srcb = colb ^ ((row & 7) << 4);
            gload_lds16(kg_ptr + (size_t)row * N_QKV + (srcb >> 1), &kT[buf][c * 8]);
        }
    };
    auto loadV = [&](int kbase, uint4 (&vv)[4]) {
        const u16* vg_ptr = qkv + (size_t)kbase * N_QKV + 2 * D_MODEL + h * HEAD_D;
#pragma unroll
        for (int i = 0; i < 4; ++i)
            vv[i] = *(const uint4*)(vg_ptr + (size_t)lane * N_QKV + w * 32 + i * 8);
    };
    auto writeV = [&](const uint4 (&vv)[4], int buf) {
#pragma unroll
        for (int i = 0; i < 4; ++i) {
            const u16* pv = (const u16*)&vv[i];
#pragma unroll
            for (int e = 0; e < 8; ++e) {
                const int d = w * 32 + i * 8 + e;
                vT[buf][d * 64 + ((((lane >> 3) ^ (d & 7)) << 3) | (lane & 7))] = pv[e];
            }
        }
    };

    // prologue: stage tile 0 into buf 0
    {
        uint4 vv[4];
        stageK(0, 0);
        loadV(0, vv);
        writeV(vv, 0);
    }
    __syncthreads();

    for (int t = 0; t < nt; ++t) {
        const int buf = t & 1;
        const int kbase = t * 64;
        const bool last = (t == nt - 1);

        // T14: issue next tile's K DMA + V reg loads BEFORE compute
        uint4 vv[4];
        if (!last) {
            stageK(kbase + 64, buf ^ 1);
            loadV(kbase + 64, vv);
        }

        // ---- QK^T on buf ----
        const u16* kTb = kT[buf];
        const u16* vTb = vT[buf];
        float st[16];
        float mx = -1e30f;
#pragma unroll
        for (int ks = 0; ks < 4; ++ks) {
            const bool active = !last || (ks <= w);
            if (active) {
                facc4 s = {};
                const int kl = ks * 16 + l15;
#pragma unroll
                for (int c = 0; c < 4; ++c) {
                    const int colb = (g4 * 16 + c * 64) ^ ((kl & 7) << 4);
                    frag8 kf = *(const frag8*)&kTb[kl * 128 + (colb >> 1)];
                    s = __builtin_amdgcn_mfma_f32_16x16x32_bf16(kf, qf[c], s, 0, 0, 0);
                }
#pragma unroll
                for (int r = 0; r < 4; ++r) {
                    float v = s[r] * scale;
                    if (last) {
                        const int key = kbase + ks * 16 + g4 * 4 + r;
                        if (key > q0 + l15) v = -1e30f;
                    }
                    st[ks * 4 + r] = v;
                    mx = fmaxf(mx, v);
                }
            } else {
#pragma unroll
                for (int r = 0; r < 4; ++r) st[ks * 4 + r] = -1e30f;
            }
        }

        mx = fmaxf(mx, __shfl_xor(mx, 16));
        mx = fmaxf(mx, __shfl_xor(mx, 32));
        // T13 defer-max
        const bool skip = __all(mx <= m_run + 8.0f);
        const float m_new = skip ? m_run : fmaxf(m_run, mx);
        const float alpha = __expf(m_run - m_new);
        float ps = 0.0f;
        uint2 pb[4];
#pragma unroll
        for (int ks = 0; ks < 4; ++ks) {
            const float p0 = __expf(st[ks * 4 + 0] - m_new);
            const float p1 = __expf(st[ks * 4 + 1] - m_new);
            const float p2 = __expf(st[ks * 4 + 2] - m_new);
            const float p3 = __expf(st[ks * 4 + 3] - m_new);
            ps += (p0 + p1) + (p2 + p3);
            pb[ks].x = (unsigned)f2b(p0) | ((unsigned)f2b(p1) << 16);
            pb[ks].y = (unsigned)f2b(p2) | ((unsigned)f2b(p3) << 16);
        }
        ps += __shfl_xor(ps, 16);
        ps += __shfl_xor(ps, 32);
        l_run = l_run * alpha + ps;
        m_run = m_new;
        if (!skip) {
#pragma unroll
            for (int c8 = 0; c8 < 8; ++c8)
#pragma unroll
                for (int r = 0; r < 4; ++r) o[c8][r] *= alpha;
        }

        // ---- PV on buf ----
#pragma unroll
        for (int kp = 0; kp < 2; ++kp) {
            const bool kp_active = !last || (kp == 0) || (w >= 2);
            if (kp_active) {
                const uint2 a = pb[2 * kp], b = pb[2 * kp + 1];
                const unsigned a0 = __shfl(a.x, src0), a1 = __shfl(a.y, src0);
                const unsigned a2 = __shfl(a.x, src1), a3 = __shfl(a.y, src1);
                const unsigned b0 = __shfl(b.x, src0), b1 = __shfl(b.y, src0);
                const unsigned b2 = __shfl(b.x, src1), b3 = __shfl(b.y, src1);
                union { unsigned u[4]; frag8 f; } pu;
                pu.u[0] = hi ? b0 : a0;
                pu.u[1] = hi ? b1 : a1;
                pu.u[2] = hi ? b2 : a2;
                pu.u[3] = hi ? b3 : a3;
                const frag8 pf = pu.f;
#pragma unroll
                for (int c8 = 0; c8 < 8; ++c8) {
                    const int d = c8 * 16 + l15;
                    const int ch = (((kp * 4 + g4) ^ (l15 & 7)) << 3);
                    frag8 vf = *(const frag8*)&vTb[d * 64 + ch];
                    o[c8] = __builtin_amdgcn_mfma_f32_16x16x32_bf16(vf, pf, o[c8], 0, 0, 0);
                }
            }
        }

        // T14 write-late: V regs -> LDS(buf^1) after compute; barrier drains K DMA too
        if (!last) writeV(vv, buf ^ 1);
        __syncthreads();
    }

    const float inv_l = 1.0f / l_run;
    u16* orow = out + (size_t)(q0 + l15) * D_MODEL + h * HEAD_D;
#pragma unroll
    for (int c8 = 0; c8 < 8; ++c8) {
        uint2 st2;
        st2.x = (unsigned)f2b(o[c8][0] * inv_l) | ((unsigned)f2b(o[c8][1] * inv_l) << 16);
        st2.y = (unsigned)f2b(o[c8][2] * inv_l) | ((unsigned)f2b(o[c8][3] * inv_l) << 16);
        *(uint2*)&orow[c8 * 16 + g4 * 4] = st2;
    }
}

// ---------------- residual + layernorm -> bf16 ----------------
__global__ __launch_bounds__(256) void ln_kernel(const float* __restrict__ a, const float* __restrict__ b,
                                                 const float* __restrict__ gamma, const float* __restrict__ beta,
                                                 u16* __restrict__ outb) {
    __shared__ float red[8];
    const int row = blockIdx.x;
    const int tid = threadIdx.x;
    const float* pa = a + (size_t)row * D_MODEL;
    const float* pb = b + (size_t)row * D_MODEL;
    float v[8];
    float s = 0.0f, s2 = 0.0f;
#pragma unroll
    for (int i = 0; i < 8; i++) {
        const int c = tid + i * 256;
        const float x = pa[c] + pb[c];
        v[i] = x;
        s += x;
        s2 += x * x;
    }
#pragma unroll
    for (int off = 32; off; off >>= 1) {
        s += __shfl_xor(s, off);
        s2 += __shfl_xor(s2, off);
    }
    if ((tid & 63) == 0) { red[(tid >> 6) * 2] = s; red[(tid >> 6) * 2 + 1] = s2; }
    __syncthreads();
    s = red[0] + red[2] + red[4] + red[6];
    s2 = red[1] + red[3] + red[5] + red[7];
    const float mean = s * (1.0f / D_MODEL);
    const float var = s2 * (1.0f / D_MODEL) - mean * mean;
    const float rstd = rsqrtf(var + 1e-5f);
#pragma unroll
    for (int i = 0; i < 8; i++) {
        const int c = tid + i * 256;
        outb[(size_t)row * D_MODEL + c] = f2b((v[i] - mean) * rstd * gamma[c] + beta[c]);
    }
}

// ---------------- bf16 residual + Σ bf16 split-K partials + bias + layernorm -> f32 ----------------
__global__ __launch_bounds__(256) void ln_part_kernel(const u16* __restrict__ hb,
                                                      const u16* __restrict__ p0, const u16* __restrict__ p1,
                                                      const u16* __restrict__ p2, const u16* __restrict__ p3,
                                                      const float* __restrict__ bias,
                                                      const float* __restrict__ gamma, const float* __restrict__ beta,
                                                      float* __restrict__ outf) {
    __shared__ float red[8];
    const int row = blockIdx.x;
    const int tid = threadIdx.x;
    const size_t rb = (size_t)row * D_MODEL;
    float v[8];
    float s = 0.0f, s2 = 0.0f;
#pragma unroll
    for (int i = 0; i < 8; i++) {
        const int c = tid + i * 256;
        float x = b2f(hb[rb + c]) + bias[c] +
                  b2f(p0[rb + c]) + b2f(p1[rb + c]) + b2f(p2[rb + c]) + b2f(p3[rb + c]);
        v[i] = x;
        s += x;
        s2 += x * x;
    }
#pragma unroll
    for (int off = 32; off; off >>= 1) {
        s += __shfl_xor(s, off);
        s2 += __shfl_xor(s2, off);
    }
    if ((tid & 63) == 0) { red[(tid >> 6) * 2] = s; red[(tid >> 6) * 2 + 1] = s2; }
    __syncthreads();
    s = red[0] + red[2] + red[4] + red[6];
    s2 = red[1] + red[3] + red[5] + red[7];
    const float mean = s * (1.0f / D_MODEL);
    const float var = s2 * (1.0f / D_MODEL) - mean * mean;
    const float rstd = rsqrtf(var + 1e-5f);
#pragma unroll
    for (int i = 0; i < 8; i++) {
        const int c = tid + i * 256;
        outf[rb + c] = (v[i] - mean) * rstd * gamma[c] + beta[c];
    }
}

extern "C" void kernel_launch(void* const* d_in, const int* in_sizes, int n_in,
                              void* d_out, int out_size, void* d_ws, size_t ws_size,
                              hipStream_t stream) {
    const float* x    = (const float*)d_in[0];
    const float* Wqkv = (const float*)d_in[1];
    const float* bqkv = (const float*)d_in[2];
    const float* Wo   = (const float*)d_in[3];
    const float* bo   = (const float*)d_in[4];
    const float* W1   = (const float*)d_in[5];
    const float* b1   = (const float*)d_in[6];
    const float* W2   = (const float*)d_in[7];
    const float* b2   = (const float*)d_in[8];
    const float* g1   = (const float*)d_in[9];
    const float* be1  = (const float*)d_in[10];
    const float* g2   = (const float*)d_in[11];
    const float* be2  = (const float*)d_in[12];

    char* ws = (char*)d_ws;
    const size_t MB = 1024 * 1024;
    u16*  xb     = (u16*)(ws + 0);          // [0,8)
    u16*  WqkvT  = (u16*)(ws + 8 * MB);     // [8,32)
    u16*  qkv    = (u16*)(ws + 32 * MB);    // [32,56)
    u16*  attn_o = (u16*)(ws + 56 * MB);    // [56,64)
    u16*  WoT    = (u16*)(ws + 8 * MB);     // [8,16)   reuses WqkvT (dead)
    float* proj  = (float*)(ws + 16 * MB);  // [16,32)
    u16*  hb     = (u16*)(ws + 0);          // [0,8)    reuses xb (dead)
    u16*  W1T    = (u16*)(ws + 8 * MB);     // [8,40)   reuses WoT+proj (dead)
    u16*  f1     = (u16*)(ws + 40 * MB);    // [40,72)
    u16*  W2T    = (u16*)(ws + 72 * MB);    // [72,104)
    u16*  part0  = (u16*)(ws + 8 * MB);     // [8,16)   reuses W1T (dead)  bf16 planes 8 MB each
    u16*  part1  = (u16*)(ws + 16 * MB);    // [16,24)
    u16*  part2  = (u16*)(ws + 24 * MB);    // [24,32)
    u16*  part3  = (u16*)(ws + 32 * MB);    // [32,40)

    // 1. x -> bf16
    cvt_bf16_kernel<<<2048, 256, 0, stream>>>(x, xb, L_SEQ * D_MODEL);
    // 2. Wqkv^T
    tr_cvt64<<<dim3(N_QKV / 64, D_MODEL / 64), 256, 0, stream>>>(Wqkv, WqkvT, D_MODEL, N_QKV);
    // 3. qkv = x @ Wqkv + bqkv (bf16), grid 192
    gemm256<1><<<dim3(192, 1, 1), 512, 0, stream>>>(xb, WqkvT, bqkv, qkv, nullptr, nullptr, nullptr, nullptr,
                                                    L_SEQ, N_QKV, D_MODEL, D_MODEL, 8);
    // 4. attention (dbuf v8)
    attn_kernel<<<dim3(L_SEQ / 64, N_HEADS), 256, 0, stream>>>(qkv, attn_o);
    // 5. Wo^T
    tr_cvt64<<<dim3(D_MODEL / 64, D_MODEL / 64), 256, 0, stream>>>(Wo, WoT, D_MODEL, D_MODEL);
    // 6. proj = attn @ Wo + bo (f32)
    gemm_bt<<<dim3(D_MODEL / 128, L_SEQ / 128), 256, 0, stream>>>(attn_o, WoT, bo, proj, L_SEQ, D_MODEL, D_MODEL);
    // 7. hb = bf16(LN(x + proj))
    ln_kernel<<<L_SEQ, 256, 0, stream>>>(x, proj, g1, be1, hb);
    // 8. W1^T
    tr_cvt64<<<dim3(D_INNER / 64, D_MODEL / 64), 256, 0, stream>>>(W1, W1T, D_MODEL, D_INNER);
    // 9. f1 = gelu(hb @ W1 + b1) (bf16), grid 256
    gemm256<2><<<dim3(256, 1, 1), 512, 0, stream>>>(hb, W1T, b1, f1, nullptr, nullptr, nullptr, nullptr,
                                                    L_SEQ, D_INNER, D_MODEL, D_MODEL, 8);
    // 10. W2^T
    tr_cvt64<<<dim3(D_MODEL / 64, D_INNER / 64), 256, 0, stream>>>(W2, W2T, D_INNER, D_MODEL);
    // 11. f2 partials = f1 @ W2 (split-K=4, bf16 planes)
    gemm256<3><<<dim3(64, 1, 4), 512, 0, stream>>>(f1, W2T, nullptr, nullptr, part0, part1, part2, part3,
                                                   L_SEQ, D_MODEL, D_INNER, 2048, 8);
    // 12. out = LN(hb + Σparts + b2)*g2+be2
    ln_part_kernel<<<L_SEQ, 256, 0, stream>>>(hb, part0, part1, part2, part3, b2, g2, be2, (float*)d_out);
}

// Round 12
// 448.236 us; speedup vs baseline: 1.0416x; 1.0416x over previous
//
#include <hip/hip_runtime.h>
#include <hip/hip_bf16.h>

typedef unsigned short u16;
typedef __attribute__((ext_vector_type(8))) short frag8;   // 8 bf16
typedef __attribute__((ext_vector_type(4))) float facc4;   // 4 f32

#define L_SEQ 2048
#define D_MODEL 2048
#define N_HEADS 16
#define HEAD_D 128
#define N_QKV 6144
#define D_INNER 8192

__device__ __forceinline__ u16 f2b(float f) {
    __hip_bfloat16 h = __float2bfloat16(f);
    return *reinterpret_cast<u16*>(&h);
}

__device__ __forceinline__ float b2f(u16 u) {
    __hip_bfloat16 h = *reinterpret_cast<__hip_bfloat16*>(&u);
    return __bfloat162float(h);
}

__device__ __forceinline__ void gload_lds16(const void* g, void* l) {
    __builtin_amdgcn_global_load_lds(
        (const __attribute__((address_space(1))) unsigned int*)g,
        (__attribute__((address_space(3))) unsigned int*)l, 16, 0, 0);
}

__device__ __forceinline__ float gelu_exact(float x) {
    return 0.5f * x * (1.0f + erff(x * 0.7071067811865475f));
}

// ---------------- elementwise f32 -> bf16 (vectorized) ----------------
__global__ __launch_bounds__(256) void cvt_bf16_kernel(const float* __restrict__ in, u16* __restrict__ out, int n) {
    const int i = (blockIdx.x * 256 + threadIdx.x) * 8;
    if (i >= n) return;
    float4 a = *(const float4*)(in + i);
    float4 b = *(const float4*)(in + i + 4);
    u16 tmp[8];
    tmp[0] = f2b(a.x); tmp[1] = f2b(a.y); tmp[2] = f2b(a.z); tmp[3] = f2b(a.w);
    tmp[4] = f2b(b.x); tmp[5] = f2b(b.y); tmp[6] = f2b(b.z); tmp[7] = f2b(b.w);
    *(uint4*)(out + i) = *(uint4*)tmp;
}

// ---------------- transpose + convert: f32 [R][C] -> bf16 [C][R], 64x64 tiles ----------------
__global__ __launch_bounds__(256) void tr_cvt64(const float* __restrict__ in, u16* __restrict__ out, int R, int C) {
    __shared__ float t[64][68];
    const int bx = blockIdx.x * 64;  // C dim
    const int by = blockIdx.y * 64;  // R dim
    const int tid = threadIdx.x;
    {
        const int r = tid >> 2;
        const int c4 = (tid & 3) * 16;
        const float* src = in + (size_t)(by + r) * C + bx + c4;
#pragma unroll
        for (int j = 0; j < 4; ++j)
            *(float4*)&t[r][c4 + 4 * j] = *(const float4*)(src + 4 * j);
    }
    __syncthreads();
    {
        const int cc = tid >> 2;
        const int rr0 = (tid & 3) * 16;
        u16 tmp[16];
#pragma unroll
        for (int j = 0; j < 16; ++j) tmp[j] = f2b(t[rr0 + j][cc]);
        u16* dst = out + (size_t)(bx + cc) * R + by + rr0;
        *(uint4*)(dst) = *(uint4*)&tmp[0];
        *(uint4*)(dst + 8) = *(uint4*)&tmp[8];
    }
}

// ---------------- gemm256 v10: 256x256, BK=64, 2 dbuf, 4-phase counted-vmcnt ----------------
// EPI: 0 f32+bias, 1 bf16+bias, 2 gelu+bf16+bias, 3 bf16 partial (plane by blockIdx.z, no bias)
template <int EPI>
__global__ __launch_bounds__(512, 2) void gemm256(const u16* __restrict__ A, const u16* __restrict__ Bt,
                                                  const float* __restrict__ bias, void* __restrict__ Cout,
                                                  u16* __restrict__ q0, u16* __restrict__ q1,
                                                  u16* __restrict__ q2, u16* __restrict__ q3,
                                                  int M, int N, int K, int kseg, int nbm) {
    __shared__ u16 lds[2 * 32768];
    const int tid = threadIdx.x;
    const int lane = tid & 63, wid = tid >> 6;
    const int wm = wid >> 2, wn = wid & 3;
    const int l15 = lane & 15, g4 = lane >> 4;

    const int nwg = gridDim.x;
    const int q8 = nwg >> 3;
    const int wg = (blockIdx.x & 7) * q8 + (blockIdx.x >> 3);
    const int bm = wg % nbm, bn = wg / nbm;
    const int kb = blockIdx.z * kseg;
    const int ksz = (blockIdx.z == (int)gridDim.z - 1) ? (K - kb) : kseg;
    const int nt = ksz >> 6;  // BK=64 tiles

    const int rr = tid >> 3;
    const int kk8 = tid & 7;
    const int srcE = (kk8 ^ (rr & 7)) << 3;
    const u16* aS = A + (size_t)(bm * 256 + rr) * K + kb + srcE;
    const u16* bS = Bt + (size_t)(bn * 256 + ((rr >> 5) << 6) + (rr & 31)) * K + kb + srcE;
    const size_t r128 = (size_t)128 * K;
    const size_t r64 = (size_t)64 * K;
    const size_t c32 = (size_t)32 * K;

    auto stA = [&](int tt, int h) {
        u16* d = &lds[((tt & 1) << 15) + (h << 13)];
        const u16* g = aS + (size_t)tt * 64 + (h ? r64 : 0);
        gload_lds16(g, d + tid * 8);
        gload_lds16(g + r128, d + 4096 + tid * 8);
    };
    auto stB = [&](int tt, int h) {
        u16* d = &lds[((tt & 1) << 15) + 16384 + (h << 13)];
        const u16* g = bS + (size_t)tt * 64 + (h ? c32 : 0);
        gload_lds16(g, d + tid * 8);
        gload_lds16(g + r128, d + 4096 + tid * 8);
    };

    const int ch0 = (g4 ^ (l15 & 7)) << 3;
    const int ch1 = ch0 ^ 32;
    const int aRdBase = (wm * 64 + l15) * 64;
    const int bRdBase = (wn * 32 + l15) * 64;

    frag8 a[4][2], b0[2][2], b1[2][2];
    facc4 acc[8][4] = {};

    auto rdA = [&](int bufo, int mh) {
#pragma unroll
        for (int mi = 0; mi < 4; ++mi) {
            const int base = bufo + mh * 8192 + aRdBase + mi * 1024;
            a[mi][0] = *(const frag8*)&lds[base + ch0];
            a[mi][1] = *(const frag8*)&lds[base + ch1];
        }
    };
    auto rdB = [&](int bufo, int nh, frag8(&bb)[2][2]) {
#pragma unroll
        for (int ni = 0; ni < 2; ++ni) {
            const int base = bufo + 16384 + nh * 8192 + bRdBase + ni * 1024;
            bb[ni][0] = *(const frag8*)&lds[base + ch0];
            bb[ni][1] = *(const frag8*)&lds[base + ch1];
        }
    };
    auto quad = [&](int mh, int nh, frag8(&bb)[2][2]) {
        __builtin_amdgcn_s_setprio(1);
#pragma unroll
        for (int kh = 0; kh < 2; ++kh)
#pragma unroll
            for (int mi = 0; mi < 4; ++mi)
#pragma unroll
                for (int ni = 0; ni < 2; ++ni)
                    acc[mh * 4 + mi][nh * 2 + ni] =
                        __builtin_amdgcn_mfma_f32_16x16x32_bf16(a[mi][kh], bb[ni][kh],
                                                                acc[mh * 4 + mi][nh * 2 + ni], 0, 0, 0);
        __builtin_amdgcn_s_setprio(0);
    };

#define SB __builtin_amdgcn_sched_barrier(0)
#define BAR __builtin_amdgcn_s_barrier()

    stA(0, 0); stB(0, 0); stB(0, 1); stA(0, 1);
    asm volatile("s_waitcnt vmcnt(4)" ::: "memory");
    BAR; SB;

    for (int t = 0; t < nt; ++t) {
        const int bufo = (t & 1) << 15;
        const bool so = (t + 1 < nt);
        // phase 0
        rdA(bufo, 0);
        rdB(bufo, 0, b0);
        if (so) stA(t + 1, 0);
        SB; BAR; SB;
        quad(0, 0, b0);
        if (so) asm volatile("s_waitcnt vmcnt(4)" ::: "memory");
        else    asm volatile("s_waitcnt vmcnt(2)" ::: "memory");
        BAR; SB;
        // phase 1
        rdB(bufo, 1, b1);
        if (so) stB(t + 1, 0);
        SB; BAR; SB;
        quad(0, 1, b1);
        if (so) asm volatile("s_waitcnt vmcnt(4)" ::: "memory");
        else    asm volatile("s_waitcnt vmcnt(0)" ::: "memory");
        BAR; SB;
        // phase 2
        rdA(bufo, 1);
        if (so) stB(t + 1, 1);
        SB; BAR; SB;
        quad(1, 0, b0);
        BAR; SB;
        // phase 3
        if (so) stA(t + 1, 1);
        SB; BAR; SB;
        quad(1, 1, b1);
        if (so) asm volatile("s_waitcnt vmcnt(4)" ::: "memory");
        BAR; SB;
    }
#undef SB
#undef BAR

    // epilogue
    const int row0 = bm * 256 + wm * 128 + g4 * 4;
    const int col0 = bn * 256 + wn * 64 + l15;
    u16* pout = nullptr;
    if (EPI == 3) {
        const int z = blockIdx.z;
        pout = (z == 0) ? q0 : (z == 1) ? q1 : (z == 2) ? q2 : q3;
    }
#pragma unroll
    for (int nf = 0; nf < 4; nf++) {
        const int col = col0 + nf * 16;
        const float bv = (EPI == 3) ? 0.0f : bias[col];
#pragma unroll
        for (int mf = 0; mf < 8; mf++) {
#pragma unroll
            for (int r = 0; r < 4; r++) {
                const int row = row0 + mf * 16 + r;
                float v = acc[mf][nf][r] + bv;
                if (EPI == 2) v = gelu_exact(v);
                if (EPI == 0)
                    ((float*)Cout)[(size_t)row * N + col] = v;
                else if (EPI == 3)
                    pout[(size_t)row * N + col] = f2b(v);
                else
                    ((u16*)Cout)[(size_t)row * N + col] = f2b(v);
            }
        }
    }
}

// ---------------- flash attention v8: K/V double-buffered, T14 async-stage split ----------------
__global__ __launch_bounds__(256) void attn_kernel(const u16* __restrict__ qkv, u16* __restrict__ out) {
    __shared__ u16 kT[2][64 * 128];
    __shared__ u16 vT[2][128 * 64];
    const int h = blockIdx.y;
    const int qb = (blockIdx.y < 8) ? ((int)gridDim.x - 1 - (int)blockIdx.x) : (int)blockIdx.x;
    const int tid = threadIdx.x;
    const int lane = tid & 63, w = tid >> 6;
    const int l15 = lane & 15, g4 = lane >> 4;
    const int q0 = qb * 64 + w * 16;
    const float scale = 0.022097086912079608f;  // 1/sqrt(2048)

    frag8 qf[4];
    {
        const u16* qrow = qkv + (size_t)(q0 + l15) * N_QKV + h * HEAD_D + g4 * 8;
#pragma unroll
        for (int c = 0; c < 4; c++) qf[c] = *(const frag8*)(qrow + c * 32);
    }

    float m_run = -1e30f, l_run = 0.0f;
    facc4 o[8] = {};

    const int src0 = ((g4 & 1) << 5) + l15;
    const int src1 = src0 + 16;
    const bool hi = (g4 & 2) != 0;

    const int nt = qb + 1;

    auto stageK = [&](int kbase, int buf) {
        const u16* kg_ptr = qkv + (size_t)kbase * N_QKV + D_MODEL + h * HEAD_D;
#pragma unroll
        for (int p = 0; p < 4; ++p) {
            const int c = p * 256 + tid;
            const int row = c >> 4;
            const int colb = (c & 15) << 4;
            const int srcb = colb ^ ((row & 7) << 4);
            gload_lds16(kg_ptr + (size_t)row * N_QKV + (srcb >> 1), &kT[buf][c * 8]);
        }
    };
    auto loadV = [&](int kbase, uint4 (&vv)[4]) {
        const u16* vg_ptr = qkv + (size_t)kbase * N_QKV + 2 * D_MODEL + h * HEAD_D;
#pragma unroll
        for (int i = 0; i < 4; ++i)
            vv[i] = *(const uint4*)(vg_ptr + (size_t)lane * N_QKV + w * 32 + i * 8);
    };
    auto writeV = [&](const uint4 (&vv)[4], int buf) {
#pragma unroll
        for (int i = 0; i < 4; ++i) {
            const u16* pv = (const u16*)&vv[i];
#pragma unroll
            for (int e = 0; e < 8; ++e) {
                const int d = w * 32 + i * 8 + e;
                vT[buf][d * 64 + ((((lane >> 3) ^ (d & 7)) << 3) | (lane & 7))] = pv[e];
            }
        }
    };

    {
        uint4 vv[4];
        stageK(0, 0);
        loadV(0, vv);
        writeV(vv, 0);
    }
    __syncthreads();

    for (int t = 0; t < nt; ++t) {
        const int buf = t & 1;
        const int kbase = t * 64;
        const bool last = (t == nt - 1);

        uint4 vv[4];
        if (!last) {
            stageK(kbase + 64, buf ^ 1);
            loadV(kbase + 64, vv);
        }

        const u16* kTb = kT[buf];
        const u16* vTb = vT[buf];
        float st[16];
        float mx = -1e30f;
#pragma unroll
        for (int ks = 0; ks < 4; ++ks) {
            const bool active = !last || (ks <= w);
            if (active) {
                facc4 s = {};
                const int kl = ks * 16 + l15;
#pragma unroll
                for (int c = 0; c < 4; ++c) {
                    const int colb = (g4 * 16 + c * 64) ^ ((kl & 7) << 4);
                    frag8 kf = *(const frag8*)&kTb[kl * 128 + (colb >> 1)];
                    s = __builtin_amdgcn_mfma_f32_16x16x32_bf16(kf, qf[c], s, 0, 0, 0);
                }
#pragma unroll
                for (int r = 0; r < 4; ++r) {
                    float v = s[r] * scale;
                    if (last) {
                        const int key = kbase + ks * 16 + g4 * 4 + r;
                        if (key > q0 + l15) v = -1e30f;
                    }
                    st[ks * 4 + r] = v;
                    mx = fmaxf(mx, v);
                }
            } else {
#pragma unroll
                for (int r = 0; r < 4; ++r) st[ks * 4 + r] = -1e30f;
            }
        }

        mx = fmaxf(mx, __shfl_xor(mx, 16));
        mx = fmaxf(mx, __shfl_xor(mx, 32));
        const bool skip = __all(mx <= m_run + 8.0f);
        const float m_new = skip ? m_run : fmaxf(m_run, mx);
        const float alpha = __expf(m_run - m_new);
        float ps = 0.0f;
        uint2 pb[4];
#pragma unroll
        for (int ks = 0; ks < 4; ++ks) {
            const float p0 = __expf(st[ks * 4 + 0] - m_new);
            const float p1 = __expf(st[ks * 4 + 1] - m_new);
            const float p2 = __expf(st[ks * 4 + 2] - m_new);
            const float p3 = __expf(st[ks * 4 + 3] - m_new);
            ps += (p0 + p1) + (p2 + p3);
            pb[ks].x = (unsigned)f2b(p0) | ((unsigned)f2b(p1) << 16);
            pb[ks].y = (unsigned)f2b(p2) | ((unsigned)f2b(p3) << 16);
        }
        ps += __shfl_xor(ps, 16);
        ps += __shfl_xor(ps, 32);
        l_run = l_run * alpha + ps;
        m_run = m_new;
        if (!skip) {
#pragma unroll
            for (int c8 = 0; c8 < 8; ++c8)
#pragma unroll
                for (int r = 0; r < 4; ++r) o[c8][r] *= alpha;
        }

#pragma unroll
        for (int kp = 0; kp < 2; ++kp) {
            const bool kp_active = !last || (kp == 0) || (w >= 2);
            if (kp_active) {
                const uint2 a = pb[2 * kp], b = pb[2 * kp + 1];
                const unsigned a0 = __shfl(a.x, src0), a1 = __shfl(a.y, src0);
                const unsigned a2 = __shfl(a.x, src1), a3 = __shfl(a.y, src1);
                const unsigned b0 = __shfl(b.x, src0), b1 = __shfl(b.y, src0);
                const unsigned b2 = __shfl(b.x, src1), b3 = __shfl(b.y, src1);
                union { unsigned u[4]; frag8 f; } pu;
                pu.u[0] = hi ? b0 : a0;
                pu.u[1] = hi ? b1 : a1;
                pu.u[2] = hi ? b2 : a2;
                pu.u[3] = hi ? b3 : a3;
                const frag8 pf = pu.f;
#pragma unroll
                for (int c8 = 0; c8 < 8; ++c8) {
                    const int d = c8 * 16 + l15;
                    const int ch = (((kp * 4 + g4) ^ (l15 & 7)) << 3);
                    frag8 vf = *(const frag8*)&vTb[d * 64 + ch];
                    o[c8] = __builtin_amdgcn_mfma_f32_16x16x32_bf16(vf, pf, o[c8], 0, 0, 0);
                }
            }
        }

        if (!last) writeV(vv, buf ^ 1);
        __syncthreads();
    }

    const float inv_l = 1.0f / l_run;
    u16* orow = out + (size_t)(q0 + l15) * D_MODEL + h * HEAD_D;
#pragma unroll
    for (int c8 = 0; c8 < 8; ++c8) {
        uint2 st2;
        st2.x = (unsigned)f2b(o[c8][0] * inv_l) | ((unsigned)f2b(o[c8][1] * inv_l) << 16);
        st2.y = (unsigned)f2b(o[c8][2] * inv_l) | ((unsigned)f2b(o[c8][3] * inv_l) << 16);
        *(uint2*)&orow[c8 * 16 + g4 * 4] = st2;
    }
}

// ---------------- LN1: f32 x + Σ4 bf16 partials + bias -> LN -> bf16 ----------------
__global__ __launch_bounds__(256) void ln1_part_kernel(const float* __restrict__ x,
                                                       const u16* __restrict__ p0, const u16* __restrict__ p1,
                                                       const u16* __restrict__ p2, const u16* __restrict__ p3,
                                                       const float* __restrict__ bias,
                                                       const float* __restrict__ gamma, const float* __restrict__ beta,
                                                       u16* __restrict__ outb) {
    __shared__ float red[8];
    const int row = blockIdx.x;
    const int tid = threadIdx.x;
    const size_t rb = (size_t)row * D_MODEL;
    float v[8];
    float s = 0.0f, s2 = 0.0f;
#pragma unroll
    for (int i = 0; i < 8; i++) {
        const int c = tid + i * 256;
        float xv = x[rb + c] + bias[c] +
                   b2f(p0[rb + c]) + b2f(p1[rb + c]) + b2f(p2[rb + c]) + b2f(p3[rb + c]);
        v[i] = xv;
        s += xv;
        s2 += xv * xv;
    }
#pragma unroll
    for (int off = 32; off; off >>= 1) {
        s += __shfl_xor(s, off);
        s2 += __shfl_xor(s2, off);
    }
    if ((tid & 63) == 0) { red[(tid >> 6) * 2] = s; red[(tid >> 6) * 2 + 1] = s2; }
    __syncthreads();
    s = red[0] + red[2] + red[4] + red[6];
    s2 = red[1] + red[3] + red[5] + red[7];
    const float mean = s * (1.0f / D_MODEL);
    const float var = s2 * (1.0f / D_MODEL) - mean * mean;
    const float rstd = rsqrtf(var + 1e-5f);
#pragma unroll
    for (int i = 0; i < 8; i++) {
        const int c = tid + i * 256;
        outb[rb + c] = f2b((v[i] - mean) * rstd * gamma[c] + beta[c]);
    }
}

// ---------------- LN2: bf16 hb + Σ4 bf16 partials + bias -> LN -> f32 ----------------
__global__ __launch_bounds__(256) void ln_part_kernel(const u16* __restrict__ hb,
                                                      const u16* __restrict__ p0, const u16* __restrict__ p1,
                                                      const u16* __restrict__ p2, const u16* __restrict__ p3,
                                                      const float* __restrict__ bias,
                                                      const float* __restrict__ gamma, const float* __restrict__ beta,
                                                      float* __restrict__ outf) {
    __shared__ float red[8];
    const int row = blockIdx.x;
    const int tid = threadIdx.x;
    const size_t rb = (size_t)row * D_MODEL;
    float v[8];
    float s = 0.0f, s2 = 0.0f;
#pragma unroll
    for (int i = 0; i < 8; i++) {
        const int c = tid + i * 256;
        float x = b2f(hb[rb + c]) + bias[c] +
                  b2f(p0[rb + c]) + b2f(p1[rb + c]) + b2f(p2[rb + c]) + b2f(p3[rb + c]);
        v[i] = x;
        s += x;
        s2 += x * x;
    }
#pragma unroll
    for (int off = 32; off; off >>= 1) {
        s += __shfl_xor(s, off);
        s2 += __shfl_xor(s2, off);
    }
    if ((tid & 63) == 0) { red[(tid >> 6) * 2] = s; red[(tid >> 6) * 2 + 1] = s2; }
    __syncthreads();
    s = red[0] + red[2] + red[4] + red[6];
    s2 = red[1] + red[3] + red[5] + red[7];
    const float mean = s * (1.0f / D_MODEL);
    const float var = s2 * (1.0f / D_MODEL) - mean * mean;
    const float rstd = rsqrtf(var + 1e-5f);
#pragma unroll
    for (int i = 0; i < 8; i++) {
        const int c = tid + i * 256;
        outf[rb + c] = (v[i] - mean) * rstd * gamma[c] + beta[c];
    }
}

extern "C" void kernel_launch(void* const* d_in, const int* in_sizes, int n_in,
                              void* d_out, int out_size, void* d_ws, size_t ws_size,
                              hipStream_t stream) {
    const float* x    = (const float*)d_in[0];
    const float* Wqkv = (const float*)d_in[1];
    const float* bqkv = (const float*)d_in[2];
    const float* Wo   = (const float*)d_in[3];
    const float* bo   = (const float*)d_in[4];
    const float* W1   = (const float*)d_in[5];
    const float* b1   = (const float*)d_in[6];
    const float* W2   = (const float*)d_in[7];
    const float* b2   = (const float*)d_in[8];
    const float* g1   = (const float*)d_in[9];
    const float* be1  = (const float*)d_in[10];
    const float* g2   = (const float*)d_in[11];
    const float* be2  = (const float*)d_in[12];

    char* ws = (char*)d_ws;
    const size_t MB = 1024 * 1024;
    // lifetimes (launch order): xb[0,8) dies after qkv GEMM; WqkvT[8,32) dies after qkv GEMM;
    // qkv[32,56) dies after attn; attn_o[56,64) dies after proj GEMM; WoT[8,16) dies after proj;
    // proj parts [16,48) die after ln1 (overlay dead qkv head); hb[0,8) (overlays dead xb);
    // W1T[8,40) (overlays WoT+parts, dead) dies after FFN1; f1[40,72) dies after FFN2;
    // W2T[72,104) dies after FFN2; FFN2 parts [8,40) (overlay dead W1T).
    u16*  xb     = (u16*)(ws + 0);
    u16*  WqkvT  = (u16*)(ws + 8 * MB);
    u16*  qkv    = (u16*)(ws + 32 * MB);
    u16*  attn_o = (u16*)(ws + 56 * MB);
    u16*  WoT    = (u16*)(ws + 8 * MB);
    u16*  pp0    = (u16*)(ws + 16 * MB);
    u16*  pp1    = (u16*)(ws + 24 * MB);
    u16*  pp2    = (u16*)(ws + 32 * MB);
    u16*  pp3    = (u16*)(ws + 40 * MB);
    u16*  hb     = (u16*)(ws + 0);
    u16*  W1T    = (u16*)(ws + 8 * MB);
    u16*  f1     = (u16*)(ws + 40 * MB);
    u16*  W2T    = (u16*)(ws + 72 * MB);
    u16*  part0  = (u16*)(ws + 8 * MB);
    u16*  part1  = (u16*)(ws + 16 * MB);
    u16*  part2  = (u16*)(ws + 24 * MB);
    u16*  part3  = (u16*)(ws + 32 * MB);

    // 1. x -> bf16
    cvt_bf16_kernel<<<2048, 256, 0, stream>>>(x, xb, L_SEQ * D_MODEL);
    // 2. Wqkv^T
    tr_cvt64<<<dim3(N_QKV / 64, D_MODEL / 64), 256, 0, stream>>>(Wqkv, WqkvT, D_MODEL, N_QKV);
    // 3. qkv = x @ Wqkv + bqkv (bf16), grid 192
    gemm256<1><<<dim3(192, 1, 1), 512, 0, stream>>>(xb, WqkvT, bqkv, qkv, nullptr, nullptr, nullptr, nullptr,
                                                    L_SEQ, N_QKV, D_MODEL, D_MODEL, 8);
    // 4. attention
    attn_kernel<<<dim3(L_SEQ / 64, N_HEADS), 256, 0, stream>>>(qkv, attn_o);
    // 5. Wo^T
    tr_cvt64<<<dim3(D_MODEL / 64, D_MODEL / 64), 256, 0, stream>>>(Wo, WoT, D_MODEL, D_MODEL);
    // 6. proj partials = attn_o @ Wo (split-K=4, bf16 planes), grid 64 x z4 = 256 blocks
    gemm256<3><<<dim3(64, 1, 4), 512, 0, stream>>>(attn_o, WoT, nullptr, nullptr, pp0, pp1, pp2, pp3,
                                                   L_SEQ, D_MODEL, D_MODEL, 512, 8);
    // 7. hb = bf16(LN(x + Σpp + bo))
    ln1_part_kernel<<<L_SEQ, 256, 0, stream>>>(x, pp0, pp1, pp2, pp3, bo, g1, be1, hb);
    // 8. W1^T
    tr_cvt64<<<dim3(D_INNER / 64, D_MODEL / 64), 256, 0, stream>>>(W1, W1T, D_MODEL, D_INNER);
    // 9. f1 = gelu(hb @ W1 + b1) (bf16), grid 256
    gemm256<2><<<dim3(256, 1, 1), 512, 0, stream>>>(hb, W1T, b1, f1, nullptr, nullptr, nullptr, nullptr,
                                                    L_SEQ, D_INNER, D_MODEL, D_MODEL, 8);
    // 10. W2^T
    tr_cvt64<<<dim3(D_MODEL / 64, D_INNER / 64), 256, 0, stream>>>(W2, W2T, D_INNER, D_MODEL);
    // 11. f2 partials = f1 @ W2 (split-K=4, bf16 planes)
    gemm256<3><<<dim3(64, 1, 4), 512, 0, stream>>>(f1, W2T, nullptr, nullptr, part0, part1, part2, part3,
                                                   L_SEQ, D_MODEL, D_INNER, 2048, 8);
    // 12. out = LN(hb + Σparts + b2)*g2+be2
    ln_part_kernel<<<L_SEQ, 256, 0, stream>>>(hb, part0, part1, part2, part3, b2, g2, be2, (float*)d_out);
}